// Round 7
// baseline (685.706 us; speedup 1.0000x reference)
//
#include <hip/hip_runtime.h>
#include <stdint.h>

typedef __attribute__((ext_vector_type(8))) short bf16x8;
typedef __attribute__((ext_vector_type(4))) float f32x4;

__device__ __forceinline__ unsigned short f2bf(float f) {
  unsigned int u = __builtin_bit_cast(unsigned int, f);
  u += 0x7FFFu + ((u >> 16) & 1u);
  return (unsigned short)(u >> 16);
}

__device__ __forceinline__ float bf2f(unsigned short s) {
  return __builtin_bit_cast(float, (unsigned int)s << 16);
}

__device__ __forceinline__ void gload_lds16(const void* g, void* l) {
  __builtin_amdgcn_global_load_lds(
      (__attribute__((address_space(1))) void*)(uintptr_t)g,
      (__attribute__((address_space(3))) void*)l,
      16, 0, 0);
}

#define BARRIER() do { asm volatile("" ::: "memory"); __builtin_amdgcn_s_barrier(); asm volatile("" ::: "memory"); } while (0)
#define WAITVM(N) asm volatile("s_waitcnt vmcnt(" #N ")" ::: "memory")

// ---------------------------------------------------------------------------
// 256x256 tile, BK=64, 8 waves (2M x 4N), TWO barriers per K-tile:
//   [24 ds_reads -> af0/af1/bf regs][stage A1(g+1)->nxt]
//   [QUAD00 QUAD01 QUAD10  (compiler-counted lgkmcnt overlaps LDS drain)]
//   BARRIER  [stage A0,B0,B1(g+2)->cur]  QUAD11  WAITVM(6)  BARRIER
// XOR-swizzled LDS (chunk c' = c ^ (row&7)) via pre-swizzled global source +
// linear global_load_lds dest; XCD-contiguous block remap.
// C[m,n] = sum_k A[m,k]*B[n,k]. A: MxK bf16 rowmajor, B: NxK bf16 rowmajor.
// MODE 0: bf16 out + f32 bias[n]
// MODE 1: fused row-softmax over N (requires nn==1, N==256, ntiles==1)
// MODE 2: f32 out + bf16 aux (residual)
// NT = K/64 power of two; G = ntiles*NT.
// ---------------------------------------------------------------------------
template <int MODE>
__global__ __launch_bounds__(512, 2) void gemm8(
    const unsigned short* __restrict__ A, const unsigned short* __restrict__ B,
    void* __restrict__ Cv, const void* __restrict__ aux, int N, int K,
    int nm, int nn, int ntiles, long sAB, long sBB, long sCB, long sXB,
    float scale)
{
  __shared__ __align__(16) char lds[131072];
  char* ldsc = lds;

  const int tid = threadIdx.x;
  const int lane = tid & 63;
  const int wid = tid >> 6;
  const int fr = lane & 15, fq = lane >> 4;

  const int nwg = gridDim.x;                 // divisible by 8 for all our shapes
  const int id = blockIdx.x;
  const int swz = (id & 7) * (nwg >> 3) + (id >> 3);
  const int per = nm * nn;
  const int t = swz / per;
  const int rem = swz - t * per;
  const int mi_ = rem / nn, ni_ = rem - mi_ * nn;
  const long bmBase = (long)mi_ * 256 * ntiles;
  const long bn = (long)ni_ * 256;

  const unsigned short* Ag = A + (long)t * sAB + bmBase * K;
  const unsigned short* Bg = B + (long)t * sBB + bn * K;
  const int NT = K >> 6;
  const int lnt = __builtin_ctz(NT);
  const int kmask = NT - 1;
  const int G = ntiles << lnt;
  const long tsA = (long)256 * K;

  // --- staging source pointers (pre-swizzled global source, linear LDS dest)
  const unsigned short* aS[2][2];
  const unsigned short* bS[2][2];
#pragma unroll
  for (int p = 0; p < 2; ++p) {
    const int q = p * 512 + tid;
    const int lr = q >> 3, cs = q & 7;
    const int cl = cs ^ (lr & 7);
#pragma unroll
    for (int h = 0; h < 2; ++h) {
      const int gA = ((lr >> 6) << 7) | (h << 6) | (lr & 63);
      const int gB = ((lr >> 5) << 6) | (h << 5) | (lr & 31);
      aS[p][h] = Ag + (long)gA * K + cl * 8;
      bS[p][h] = Bg + (long)gB * K + cl * 8;
    }
  }

#define AOFF(g) (((long)((g) & kmask) << 6) + (long)((g) >> lnt) * tsA)
#define BOFF(g) ((long)((g) & kmask) << 6)

  // --- swizzled ds_read byte offsets (within a half): row*128 + chunk'*16
  const int c0 = ((fq ^ (fr & 3)) + ((fr >> 2) & 1) * 4) * 16;   // ks=0 chunk
  const int aRd = ((wid >> 2) * 64 + fr) * 128 + c0;  // + mi*16384 + i*2048 (^64 ks=1)
  const int bRd = ((wid & 3) * 32 + fr) * 128 + c0;   // + nj*16384 + j*2048 (^64 ks=1)

  f32x4 acc[2][2][4][2];
#pragma unroll
  for (int a = 0; a < 2; a++)
#pragma unroll
    for (int b = 0; b < 2; b++)
#pragma unroll
      for (int i = 0; i < 4; i++)
#pragma unroll
        for (int j = 0; j < 2; j++)
#pragma unroll
          for (int r = 0; r < 4; r++) acc[a][b][i][j][r] = 0.f;

  bf16x8 af0[4][2], af1[4][2], bfr[2][2][2];

#define STAGE(srcArr, aoff, h, eoff, b) do {                                  \
  _Pragma("unroll")                                                           \
  for (int p = 0; p < 2; ++p)                                                 \
    gload_lds16(srcArr[p][h] + (eoff),                                        \
                ldsc + (aoff) + ((b) << 16) + ((h) << 14) + (p << 13) + (wid << 10)); \
} while (0)

#define LDA(dst, mi, cub) do {                                                \
  _Pragma("unroll")                                                           \
  for (int i = 0; i < 4; ++i) {                                               \
    dst[i][0] = *(const bf16x8*)(ldsc + (cub) + (mi) * 16384 + aRd + i * 2048);        \
    dst[i][1] = *(const bf16x8*)(ldsc + (cub) + (mi) * 16384 + (aRd ^ 64) + i * 2048); \
  }                                                                           \
} while (0)

#define LDB(nj, cub) do {                                                     \
  _Pragma("unroll")                                                           \
  for (int j = 0; j < 2; ++j) {                                               \
    bfr[nj][j][0] = *(const bf16x8*)(ldsc + 32768 + (cub) + (nj) * 16384 + bRd + j * 2048);        \
    bfr[nj][j][1] = *(const bf16x8*)(ldsc + 32768 + (cub) + (nj) * 16384 + (bRd ^ 64) + j * 2048); \
  }                                                                           \
} while (0)

#define QUAD(AF, mi, nj) do {                                                 \
  __builtin_amdgcn_s_setprio(1);                                              \
  _Pragma("unroll")                                                           \
  for (int i = 0; i < 4; ++i)                                                 \
  _Pragma("unroll")                                                           \
  for (int j = 0; j < 2; ++j) {                                               \
    acc[mi][nj][i][j] = __builtin_amdgcn_mfma_f32_16x16x32_bf16(              \
        AF[i][0], bfr[nj][j][0], acc[mi][nj][i][j], 0, 0, 0);                 \
    acc[mi][nj][i][j] = __builtin_amdgcn_mfma_f32_16x16x32_bf16(              \
        AF[i][1], bfr[nj][j][1], acc[mi][nj][i][j], 0, 0, 0);                 \
  }                                                                           \
  __builtin_amdgcn_s_setprio(0);                                              \
} while (0)

  // --- prologue: g0 {A0,B0,B1,A1} -> buf0; g1 {A0,B0,B1} -> buf1 (14 loads)
  STAGE(aS, 0, 0, AOFF(0), 0);
  STAGE(bS, 32768, 0, BOFF(0), 0);
  STAGE(bS, 32768, 1, BOFF(0), 0);
  STAGE(aS, 0, 1, AOFF(0), 0);
  if (G > 1) {
    STAGE(aS, 0, 0, AOFF(1), 1);
    STAGE(bS, 32768, 0, BOFF(1), 1);
    STAGE(bS, 32768, 1, BOFF(1), 1);
    WAITVM(6);
  } else {
    WAITVM(0);
  }
  BARRIER();

  for (int g = 0; g < G; ++g) {
    const int cur = g & 1;
    const int cub = cur << 16;
    // all 24 fragment reads for this K-tile (compiler-counted lgkm waits)
    LDA(af0, 0, cub);
    LDB(0, cub);
    LDB(1, cub);
    LDA(af1, 1, cub);
    if (g + 1 < G) STAGE(aS, 0, 1, AOFF(g + 1), cur ^ 1);  // A1(g+1)->nxt
    QUAD(af0, 0, 0);   // waits first 12 reads; rest drain under MFMA
    QUAD(af0, 0, 1);
    QUAD(af1, 1, 0);   // lgkm(0) holds past here for every wave
    BARRIER();         // safe to overwrite cur now
    if (g + 2 < G) {
      STAGE(aS, 0, 0, AOFF(g + 2), cur);
      STAGE(bS, 32768, 0, BOFF(g + 2), cur);
      STAGE(bS, 32768, 1, BOFF(g + 2), cur);
    }
    QUAD(af1, 1, 1);
    if (g + 2 < G) { WAITVM(6); } else { WAITVM(0); }
    BARRIER();

    if ((g & kmask) != kmask) continue;

    // ---- per-tile epilogue ----
    const int s = g >> lnt;
    const long bm = bmBase + (long)s * 256;
    if (MODE == 1) {
      // fused row-softmax of (acc*scale) over N=256; attn bf16 out.
      float* red  = (float*)ldsc;            // [256][4]
      float* red2 = (float*)(ldsc + 4096);   // [256][4]
      const int wc = wid & 3;
      const int rbase = (wid >> 2) * 128;
#pragma unroll
      for (int mi = 0; mi < 2; ++mi)
#pragma unroll
        for (int i = 0; i < 4; ++i)
#pragma unroll
          for (int r = 0; r < 4; ++r) {
            float m = fmaxf(fmaxf(acc[mi][0][i][0][r], acc[mi][0][i][1][r]),
                            fmaxf(acc[mi][1][i][0][r], acc[mi][1][i][1][r]));
#pragma unroll
            for (int o = 1; o <= 8; o <<= 1) m = fmaxf(m, __shfl_xor(m, o));
            if (fr == 0) red[(rbase + mi * 64 + i * 16 + fq * 4 + r) * 4 + wc] = m;
          }
      BARRIER();
#pragma unroll
      for (int mi = 0; mi < 2; ++mi)
#pragma unroll
        for (int i = 0; i < 4; ++i)
#pragma unroll
          for (int r = 0; r < 4; ++r) {
            const int rl = rbase + mi * 64 + i * 16 + fq * 4 + r;
            f32x4 mm = *(f32x4*)&red[rl * 4];
            const float M = fmaxf(fmaxf(mm[0], mm[1]), fmaxf(mm[2], mm[3]));
            float sm = 0.f;
#pragma unroll
            for (int nj = 0; nj < 2; ++nj)
#pragma unroll
              for (int j = 0; j < 2; ++j) {
                float e = __expf((acc[mi][nj][i][j][r] - M) * scale);
                acc[mi][nj][i][j][r] = e;
                sm += e;
              }
#pragma unroll
            for (int o = 1; o <= 8; o <<= 1) sm += __shfl_xor(sm, o);
            if (fr == 0) red2[rl * 4 + wc] = sm;
          }
      BARRIER();
      unsigned short* C = (unsigned short*)Cv + (long)t * sCB;
#pragma unroll
      for (int mi = 0; mi < 2; ++mi)
#pragma unroll
        for (int i = 0; i < 4; ++i)
#pragma unroll
          for (int r = 0; r < 4; ++r) {
            const int rl = rbase + mi * 64 + i * 16 + fq * 4 + r;
            f32x4 sv = *(f32x4*)&red2[rl * 4];
            const float inv = 1.0f / (sv[0] + sv[1] + sv[2] + sv[3]);
            const long gr = bm + rl;
#pragma unroll
            for (int nj = 0; nj < 2; ++nj)
#pragma unroll
              for (int j = 0; j < 2; ++j) {
                const long gcol = bn + wc * 64 + nj * 32 + j * 16 + fr;
                C[gr * N + gcol] = f2bf(acc[mi][nj][i][j][r] * inv);
              }
          }
    } else {
#pragma unroll
      for (int mi = 0; mi < 2; ++mi)
#pragma unroll
        for (int nj = 0; nj < 2; ++nj)
#pragma unroll
          for (int i = 0; i < 4; ++i) {
            const long grow0 = bm + (wid >> 2) * 128 + mi * 64 + i * 16 + fq * 4;
#pragma unroll
            for (int j = 0; j < 2; ++j) {
              const long gcol = bn + (wid & 3) * 64 + nj * 32 + j * 16 + fr;
              if (MODE == 0) {
                unsigned short* C = (unsigned short*)Cv + (long)t * sCB;
                const float bv = ((const float*)aux)[gcol];
#pragma unroll
                for (int r = 0; r < 4; ++r)
                  C[(grow0 + r) * N + gcol] = f2bf(acc[mi][nj][i][j][r] + bv);
              } else {
                float* C = (float*)Cv + (long)t * sCB;
                const unsigned short* X = (const unsigned short*)aux + (long)t * sXB;
#pragma unroll
                for (int r = 0; r < 4; ++r) {
                  const long idx = (grow0 + r) * N + gcol;
                  C[idx] = acc[mi][nj][i][j][r] + bf2f(X[idx]);
                }
              }
            }
          }
      if (g + 1 < G) {
#pragma unroll
        for (int a = 0; a < 2; a++)
#pragma unroll
          for (int b = 0; b < 2; b++)
#pragma unroll
            for (int i = 0; i < 4; i++)
#pragma unroll
              for (int j = 0; j < 2; j++)
#pragma unroll
                for (int r = 0; r < 4; r++) acc[a][b][i][j][r] = 0.f;
      }
    }
  }
#undef STAGE
#undef LDA
#undef LDB
#undef QUAD
#undef AOFF
#undef BOFF
}

__global__ __launch_bounds__(256) void convert_f32_bf16(
    const float* __restrict__ in, unsigned short* __restrict__ out, long n) {
  long i = ((long)blockIdx.x * 256 + threadIdx.x) * 4;
  long stride = (long)gridDim.x * 1024;
  for (; i < n; i += stride) {
    float4 v = *(const float4*)(in + i);
    ushort4 o;
    o.x = f2bf(v.x); o.y = f2bf(v.y); o.z = f2bf(v.z); o.w = f2bf(v.w);
    *(ushort4*)(out + i) = o;
  }
}

// slow_feature [64][256][1024] f32 -> slowBf [t][k][d] bf16 AND slowT [t][d][k] bf16
__global__ __launch_bounds__(256) void convert_transpose_slow(
    const float* __restrict__ in, unsigned short* __restrict__ outR,
    unsigned short* __restrict__ outT) {
  __shared__ unsigned short tile[32][33];
  int t = blockIdx.z;
  int d0 = blockIdx.x * 32;
  int k0 = blockIdx.y * 32;
  const float* ip = in + (long)t * 256 * 1024;
  unsigned short* rp = outR + (long)t * 256 * 1024;
  unsigned short* tp = outT + (long)t * 1024 * 256;
  int tx = threadIdx.x & 31, ty = threadIdx.x >> 5;
#pragma unroll
  for (int p = 0; p < 4; p++) {
    int k = ty + p * 8;
    unsigned short b = f2bf(ip[(long)(k0 + k) * 1024 + d0 + tx]);
    tile[k][tx] = b;
    rp[(long)(k0 + k) * 1024 + d0 + tx] = b;
  }
  __syncthreads();
#pragma unroll
  for (int p = 0; p < 4; p++) {
    int d = ty + p * 8;
    tp[(long)(d0 + d) * 256 + k0 + tx] = tile[tx][d];
  }
}

extern "C" void kernel_launch(void* const* d_in, const int* in_sizes, int n_in,
                              void* d_out, int out_size, void* d_ws, size_t ws_size,
                              hipStream_t stream) {
  const float* fastF     = (const float*)d_in[0];  // [64,1024,1024]
  const float* slowF     = (const float*)d_in[1];  // [64,256,1024]
  const float* fastW     = (const float*)d_in[2];  // [1024,1024]
  const float* fast_bias = (const float*)d_in[3];  // [1024]
  const float* slowW     = (const float*)d_in[4];  // [1024,1024]
  const float* slow_bias = (const float*)d_in[5];  // [1024]
  float* out = (float*)d_out;

  char* ws = (char*)d_ws;
  // layout: fastBf [0,128M) alive until ctx; fastKey [128M,256M);
  // attnBf [256M,288M) over dead slowBf; slowT [288M,320M);
  // slowKey [320M,352M); weights at 352M+.
  unsigned short* fastBf  = (unsigned short*)(ws);
  unsigned short* fastKey = (unsigned short*)(ws + 134217728L);
  unsigned short* slowBf  = (unsigned short*)(ws + 268435456L);
  unsigned short* attnBf  = (unsigned short*)(ws + 268435456L);  // reuses slowBf
  unsigned short* slowT   = (unsigned short*)(ws + 301989888L);
  unsigned short* slowKey = (unsigned short*)(ws + 335544320L);
  unsigned short* fWb     = (unsigned short*)(ws + 369098752L);
  unsigned short* sWb     = (unsigned short*)(ws + 371195904L);

  convert_f32_bf16<<<2048, 256, 0, stream>>>(fastF, fastBf, 67108864L);
  convert_f32_bf16<<<1024, 256, 0, stream>>>(fastW, fWb, 1048576L);
  convert_f32_bf16<<<1024, 256, 0, stream>>>(slowW, sWb, 1048576L);
  convert_transpose_slow<<<dim3(32, 8, 64), 256, 0, stream>>>(slowF, slowBf, slowT);

  // slow_key = slow @ slowW^T + slow_b : M=16384, N=1024, K=1024 (G=16)
  gemm8<0><<<256, 512, 0, stream>>>(slowBf, sWb, slowKey, slow_bias,
      1024, 1024, 64, 4, 1, 0, 0, 0, 0, 1.f);
  // fast_key = fast @ fastW^T + fast_b : M=65536, N=1024, K=1024 (G=16)
  gemm8<0><<<1024, 512, 0, stream>>>(fastBf, fWb, fastKey, fast_bias,
      1024, 1024, 256, 4, 1, 0, 0, 0, 0, 1.f);
  // attn[t] = softmax(fast_key[t] @ slow_key[t]^T / 32) : M=1024, N=256, K=1024 (G=16)
  gemm8<1><<<256, 512, 0, stream>>>(fastKey, slowKey, attnBf, nullptr,
      256, 1024, 4, 1, 1, 1048576L, 262144L, 262144L, 0, 0.03125f);
  // out[t] = attn[t] @ slow_T[t]^T + bf16(fast[t]) : M=1024, N=1024, K=256 (G=4)
  gemm8<2><<<1024, 512, 0, stream>>>(attnBf, slowT, out, fastBf,
      1024, 256, 4, 4, 1, 262144L, 262144L, 1048576L, 1048576L, 1.f);
}

// Round 8
// 469.760 us; speedup vs baseline: 1.4597x; 1.4597x over previous
//
#include <hip/hip_runtime.h>
#include <stdint.h>

typedef __attribute__((ext_vector_type(8))) short bf16x8;
typedef __attribute__((ext_vector_type(4))) float f32x4;

__device__ __forceinline__ unsigned short f2bf(float f) {
  unsigned int u = __builtin_bit_cast(unsigned int, f);
  u += 0x7FFFu + ((u >> 16) & 1u);
  return (unsigned short)(u >> 16);
}

__device__ __forceinline__ float bf2f(unsigned short s) {
  return __builtin_bit_cast(float, (unsigned int)s << 16);
}

__device__ __forceinline__ void gload_lds16(const void* g, void* l) {
  __builtin_amdgcn_global_load_lds(
      (__attribute__((address_space(1))) void*)(uintptr_t)g,
      (__attribute__((address_space(3))) void*)l,
      16, 0, 0);
}

#define BARRIER() do { asm volatile("" ::: "memory"); __builtin_amdgcn_s_barrier(); asm volatile("" ::: "memory"); } while (0)
#define WAITVM(N) asm volatile("s_waitcnt vmcnt(" #N ")" ::: "memory")

// ---------------------------------------------------------------------------
// 256x256 tile, BK=64, 8 waves (2M x 4N), 8-phase schedule, counted vmcnt,
// XOR-swizzled LDS (chunk c' = c ^ (row&7)), XCD-contiguous block remap.
// ROUND-5 VERIFIED LOOP (do not restructure): fragments loaded into registers
// strictly before any prefetch that overwrites their LDS region is issued;
// LDB interleaved with QUADs keeps live fragment set small (no spill).
// C[m,n] = sum_k A[m,k]*B[n,k]. A: MxK bf16 rowmajor, B: NxK bf16 rowmajor.
// MODE 0: bf16 out + f32 bias[n]
// MODE 1: fused row-softmax over N (requires nn==1, N==256): attn bf16 out
// MODE 2: f32 out + bf16 aux (residual)
// ---------------------------------------------------------------------------
template <int MODE>
__global__ __launch_bounds__(512, 2) void gemm8(
    const unsigned short* __restrict__ A, const unsigned short* __restrict__ B,
    void* __restrict__ Cv, const void* __restrict__ aux, int N, int K,
    int nm, int nn, long sAB, long sBB, long sCB, long sXB, float scale)
{
  __shared__ __align__(16) char lds[131072];
  char* ldsc = lds;

  const int tid = threadIdx.x;
  const int lane = tid & 63;
  const int wid = tid >> 6;
  const int fr = lane & 15, fq = lane >> 4;

  const int nwg = gridDim.x;                 // divisible by 8 for all our shapes
  const int id = blockIdx.x;
  const int swz = (id & 7) * (nwg >> 3) + (id >> 3);
  const int per = nm * nn;
  const int t = swz / per;
  const int rem = swz - t * per;
  const int mi_ = rem / nn, ni_ = rem - mi_ * nn;
  const long bm = (long)mi_ * 256, bn = (long)ni_ * 256;

  const unsigned short* Ag = A + (long)t * sAB + bm * K;
  const unsigned short* Bg = B + (long)t * sBB + bn * K;
  const int NT = K >> 6;

  // --- staging source pointers (pre-swizzled global source, linear LDS dest)
  const unsigned short* aS[2][2];
  const unsigned short* bS[2][2];
#pragma unroll
  for (int p = 0; p < 2; ++p) {
    const int q = p * 512 + tid;
    const int lr = q >> 3, cs = q & 7;
    const int cl = cs ^ (lr & 7);
#pragma unroll
    for (int h = 0; h < 2; ++h) {
      const int gA = ((lr >> 6) << 7) | (h << 6) | (lr & 63);
      const int gB = ((lr >> 5) << 6) | (h << 5) | (lr & 31);
      aS[p][h] = Ag + (long)gA * K + cl * 8;
      bS[p][h] = Bg + (long)gB * K + cl * 8;
    }
  }

  // --- swizzled ds_read byte offsets (within a half): row*128 + chunk'*16
  const int c0 = ((fq ^ (fr & 3)) + ((fr >> 2) & 1) * 4) * 16;   // ks=0 chunk
  const int aRd = ((wid >> 2) * 64 + fr) * 128 + c0;  // + mi*16384 + i*2048 (^64 ks=1)
  const int bRd = ((wid & 3) * 32 + fr) * 128 + c0;   // + nj*16384 + j*2048 (^64 ks=1)

  f32x4 acc[2][2][4][2];
#pragma unroll
  for (int a = 0; a < 2; a++)
#pragma unroll
    for (int b = 0; b < 2; b++)
#pragma unroll
      for (int i = 0; i < 4; i++)
#pragma unroll
        for (int j = 0; j < 2; j++)
#pragma unroll
          for (int r = 0; r < 4; r++) acc[a][b][i][j][r] = 0.f;

  bf16x8 af[4][2], bf[2][2][2];

// stage one half-tile (2 x global_load_lds per thread). aoff: 0=A, 32768=B.
#define STAGE(srcArr, aoff, h, ktv, b) do {                                   \
  _Pragma("unroll")                                                           \
  for (int p = 0; p < 2; ++p)                                                 \
    gload_lds16(srcArr[p][h] + ((long)(ktv) << 6),                            \
                ldsc + (aoff) + ((b) << 16) + ((h) << 14) + (p << 13) + (wid << 10)); \
} while (0)

#define LDA(mi, cub) do {                                                     \
  _Pragma("unroll")                                                           \
  for (int i = 0; i < 4; ++i) {                                               \
    af[i][0] = *(const bf16x8*)(ldsc + (cub) + (mi) * 16384 + aRd + i * 2048);        \
    af[i][1] = *(const bf16x8*)(ldsc + (cub) + (mi) * 16384 + (aRd ^ 64) + i * 2048); \
  }                                                                           \
} while (0)

#define LDB(nj, cub) do {                                                     \
  _Pragma("unroll")                                                           \
  for (int j = 0; j < 2; ++j) {                                               \
    bf[nj][j][0] = *(const bf16x8*)(ldsc + 32768 + (cub) + (nj) * 16384 + bRd + j * 2048);        \
    bf[nj][j][1] = *(const bf16x8*)(ldsc + 32768 + (cub) + (nj) * 16384 + (bRd ^ 64) + j * 2048); \
  }                                                                           \
} while (0)

#define QUAD(mi, nj) do {                                                     \
  __builtin_amdgcn_s_setprio(1);                                              \
  _Pragma("unroll")                                                           \
  for (int i = 0; i < 4; ++i)                                                 \
  _Pragma("unroll")                                                           \
  for (int j = 0; j < 2; ++j) {                                               \
    acc[mi][nj][i][j] = __builtin_amdgcn_mfma_f32_16x16x32_bf16(              \
        af[i][0], bf[nj][j][0], acc[mi][nj][i][j], 0, 0, 0);                  \
    acc[mi][nj][i][j] = __builtin_amdgcn_mfma_f32_16x16x32_bf16(              \
        af[i][1], bf[nj][j][1], acc[mi][nj][i][j], 0, 0, 0);                  \
  }                                                                           \
  __builtin_amdgcn_s_setprio(0);                                              \
} while (0)

  // --- prologue: kt0 {A0,B0,B1,A1} -> buf0; kt1 {A0,B0,B1} -> buf1
  STAGE(aS, 0, 0, 0, 0);
  STAGE(bS, 32768, 0, 0, 0);
  STAGE(bS, 32768, 1, 0, 0);
  STAGE(aS, 0, 1, 0, 0);
  if (NT > 1) {
    STAGE(aS, 0, 0, 1, 1);
    STAGE(bS, 32768, 0, 1, 1);
    STAGE(bS, 32768, 1, 1, 1);
    WAITVM(6);
  } else {
    WAITVM(0);
  }
  BARRIER();

  for (int kt = 0; kt < NT; ++kt) {
    const int cur = kt & 1, nxt = cur ^ 1;
    const int cub = cur << 16;
    // P0: (mi0,nj0); prefetch kt+1's A1 -> nxt
    LDA(0, cub);
    LDB(0, cub);
    if (kt + 1 < NT) STAGE(aS, 0, 1, kt + 1, nxt);
    BARRIER();
    QUAD(0, 0);
    BARRIER();
    // P1: (mi0,nj1); prefetch kt+2's A0 -> cur (A0 last read in P0)
    LDB(1, cub);
    if (kt + 2 < NT) STAGE(aS, 0, 0, kt + 2, cur);
    BARRIER();
    QUAD(0, 1);
    BARRIER();
    // P2: (mi1,nj0); prefetch kt+2's B0 -> cur (B0 last read in P0)
    LDA(1, cub);
    if (kt + 2 < NT) STAGE(bS, 32768, 0, kt + 2, cur);
    BARRIER();
    QUAD(1, 0);
    BARRIER();
    // P3: (mi1,nj1); prefetch kt+2's B1 -> cur (B1 last read in P1)
    if (kt + 2 < NT) {
      STAGE(bS, 32768, 1, kt + 2, cur);
      QUAD(1, 1);
      WAITVM(6);           // keep 3 half-tiles (kt+2 A0,B0,B1) in flight
    } else {
      QUAD(1, 1);
      WAITVM(0);           // epilogue drain (kt+1's A1 if issued)
    }
    BARRIER();
  }

  // --- epilogue
  if (MODE == 1) {
    // fused row-softmax of (acc*scale) over the full N=256 row; attn bf16 out.
    float* red  = (float*)ldsc;            // [256][4]
    float* red2 = (float*)(ldsc + 4096);   // [256][4]
    const int wc = wid & 3;
    const int rbase = (wid >> 2) * 128;
    // pass 1: per-row wave-partial max (this wave's 64 columns)
#pragma unroll
    for (int mi = 0; mi < 2; ++mi)
#pragma unroll
      for (int i = 0; i < 4; ++i)
#pragma unroll
        for (int r = 0; r < 4; ++r) {
          float m = fmaxf(fmaxf(acc[mi][0][i][0][r], acc[mi][0][i][1][r]),
                          fmaxf(acc[mi][1][i][0][r], acc[mi][1][i][1][r]));
#pragma unroll
          for (int o = 1; o <= 8; o <<= 1) m = fmaxf(m, __shfl_xor(m, o));
          if (fr == 0) red[(rbase + mi * 64 + i * 16 + fq * 4 + r) * 4 + wc] = m;
        }
    BARRIER();
    // pass 2: exp + per-row wave-partial sum
#pragma unroll
    for (int mi = 0; mi < 2; ++mi)
#pragma unroll
      for (int i = 0; i < 4; ++i)
#pragma unroll
        for (int r = 0; r < 4; ++r) {
          const int rl = rbase + mi * 64 + i * 16 + fq * 4 + r;
          f32x4 mm = *(f32x4*)&red[rl * 4];
          const float M = fmaxf(fmaxf(mm[0], mm[1]), fmaxf(mm[2], mm[3]));
          float s = 0.f;
#pragma unroll
          for (int nj = 0; nj < 2; ++nj)
#pragma unroll
            for (int j = 0; j < 2; ++j) {
              float e = __expf((acc[mi][nj][i][j][r] - M) * scale);
              acc[mi][nj][i][j][r] = e;
              s += e;
            }
#pragma unroll
          for (int o = 1; o <= 8; o <<= 1) s += __shfl_xor(s, o);
          if (fr == 0) red2[rl * 4 + wc] = s;
        }
    BARRIER();
    // pass 3: normalize + store bf16
    unsigned short* C = (unsigned short*)Cv + (long)t * sCB;
#pragma unroll
    for (int mi = 0; mi < 2; ++mi)
#pragma unroll
      for (int i = 0; i < 4; ++i)
#pragma unroll
        for (int r = 0; r < 4; ++r) {
          const int rl = rbase + mi * 64 + i * 16 + fq * 4 + r;
          f32x4 sv = *(f32x4*)&red2[rl * 4];
          const float inv = 1.0f / (sv[0] + sv[1] + sv[2] + sv[3]);
          const long gr = bm + rl;
#pragma unroll
          for (int nj = 0; nj < 2; ++nj)
#pragma unroll
            for (int j = 0; j < 2; ++j) {
              const long gcol = bn + wc * 64 + nj * 32 + j * 16 + fr;
              C[gr * N + gcol] = f2bf(acc[mi][nj][i][j][r] * inv);
            }
        }
  } else {
#pragma unroll
    for (int mi = 0; mi < 2; ++mi)
#pragma unroll
      for (int nj = 0; nj < 2; ++nj)
#pragma unroll
        for (int i = 0; i < 4; ++i) {
          const long grow0 = bm + (wid >> 2) * 128 + mi * 64 + i * 16 + fq * 4;
#pragma unroll
          for (int j = 0; j < 2; ++j) {
            const long gcol = bn + (wid & 3) * 64 + nj * 32 + j * 16 + fr;
            if (MODE == 0) {
              unsigned short* C = (unsigned short*)Cv + (long)t * sCB;
              const float bv = ((const float*)aux)[gcol];
#pragma unroll
              for (int r = 0; r < 4; ++r)
                C[(grow0 + r) * N + gcol] = f2bf(acc[mi][nj][i][j][r] + bv);
            } else {
              float* C = (float*)Cv + (long)t * sCB;
              const unsigned short* X = (const unsigned short*)aux + (long)t * sXB;
#pragma unroll
              for (int r = 0; r < 4; ++r) {
                const long idx = (grow0 + r) * N + gcol;
                C[idx] = acc[mi][nj][i][j][r] + bf2f(X[idx]);
              }
            }
          }
        }
  }
#undef STAGE
#undef LDA
#undef LDB
#undef QUAD
}

__global__ __launch_bounds__(256) void convert_f32_bf16(
    const float* __restrict__ in, unsigned short* __restrict__ out, long n) {
  long i = ((long)blockIdx.x * 256 + threadIdx.x) * 4;
  long stride = (long)gridDim.x * 1024;
  for (; i < n; i += stride) {
    float4 v = *(const float4*)(in + i);
    ushort4 o;
    o.x = f2bf(v.x); o.y = f2bf(v.y); o.z = f2bf(v.z); o.w = f2bf(v.w);
    *(ushort4*)(out + i) = o;
  }
}

// slow_feature [64][256][1024] f32 -> slowBf [t][k][d] bf16 AND slowT [t][d][k] bf16
__global__ __launch_bounds__(256) void convert_transpose_slow(
    const float* __restrict__ in, unsigned short* __restrict__ outR,
    unsigned short* __restrict__ outT) {
  __shared__ unsigned short tile[32][33];
  int t = blockIdx.z;
  int d0 = blockIdx.x * 32;
  int k0 = blockIdx.y * 32;
  const float* ip = in + (long)t * 256 * 1024;
  unsigned short* rp = outR + (long)t * 256 * 1024;
  unsigned short* tp = outT + (long)t * 1024 * 256;
  int tx = threadIdx.x & 31, ty = threadIdx.x >> 5;
#pragma unroll
  for (int p = 0; p < 4; p++) {
    int k = ty + p * 8;
    unsigned short b = f2bf(ip[(long)(k0 + k) * 1024 + d0 + tx]);
    tile[k][tx] = b;
    rp[(long)(k0 + k) * 1024 + d0 + tx] = b;
  }
  __syncthreads();
#pragma unroll
  for (int p = 0; p < 4; p++) {
    int d = ty + p * 8;
    tp[(long)(d0 + d) * 256 + k0 + tx] = tile[tx][d];
  }
}

extern "C" void kernel_launch(void* const* d_in, const int* in_sizes, int n_in,
                              void* d_out, int out_size, void* d_ws, size_t ws_size,
                              hipStream_t stream) {
  const float* fastF     = (const float*)d_in[0];  // [64,1024,1024]
  const float* slowF     = (const float*)d_in[1];  // [64,256,1024]
  const float* fastW     = (const float*)d_in[2];  // [1024,1024]
  const float* fast_bias = (const float*)d_in[3];  // [1024]
  const float* slowW     = (const float*)d_in[4];  // [1024,1024]
  const float* slow_bias = (const float*)d_in[5];  // [1024]
  float* out = (float*)d_out;

  char* ws = (char*)d_ws;
  // layout: fastBf [0,128M) alive until ctx (residual); fastKey [128M,256M);
  // attnBf [256M,288M) over dead slowBf; slowT [288M,320M);
  // slowKey [320M,352M); weights at 352M+.
  unsigned short* fastBf  = (unsigned short*)(ws);
  unsigned short* fastKey = (unsigned short*)(ws + 134217728L);
  unsigned short* slowBf  = (unsigned short*)(ws + 268435456L);
  unsigned short* attnBf  = (unsigned short*)(ws + 268435456L);  // reuses slowBf
  unsigned short* slowT   = (unsigned short*)(ws + 301989888L);
  unsigned short* slowKey = (unsigned short*)(ws + 335544320L);
  unsigned short* fWb     = (unsigned short*)(ws + 369098752L);
  unsigned short* sWb     = (unsigned short*)(ws + 371195904L);

  convert_f32_bf16<<<2048, 256, 0, stream>>>(fastF, fastBf, 67108864L);
  convert_f32_bf16<<<1024, 256, 0, stream>>>(fastW, fWb, 1048576L);
  convert_f32_bf16<<<1024, 256, 0, stream>>>(slowW, sWb, 1048576L);
  convert_transpose_slow<<<dim3(32, 8, 64), 256, 0, stream>>>(slowF, slowBf, slowT);

  // slow_key = slow @ slowW^T + slow_b : M=16384, N=1024, K=1024 (NT=16)
  gemm8<0><<<64 * 4, 512, 0, stream>>>(slowBf, sWb, slowKey, slow_bias,
      1024, 1024, 64, 4, 0, 0, 0, 0, 1.f);
  // fast_key = fast @ fastW^T + fast_b : M=65536, N=1024, K=1024 (NT=16)
  gemm8<0><<<256 * 4, 512, 0, stream>>>(fastBf, fWb, fastKey, fast_bias,
      1024, 1024, 256, 4, 0, 0, 0, 0, 1.f);
  // attn[t] = softmax(fast_key[t] @ slow_key[t]^T / 32) : M=1024, N=256, K=1024 (NT=16)
  gemm8<1><<<4 * 1 * 64, 512, 0, stream>>>(fastKey, slowKey, attnBf, nullptr,
      256, 1024, 4, 1, 1048576L, 262144L, 262144L, 0, 0.03125f);
  // out[t] = attn[t] @ slow_T[t]^T + bf16(fast[t]) : M=1024, N=1024, K=256 (NT=4)
  gemm8<2><<<4 * 4 * 64, 512, 0, stream>>>(attnBf, slowT, out, fastBf,
      1024, 256, 4, 4, 262144L, 262144L, 1048576L, 1048576L, 1.f);
}

// Round 9
// 469.459 us; speedup vs baseline: 1.4606x; 1.0006x over previous
//
#include <hip/hip_runtime.h>
#include <stdint.h>

typedef __attribute__((ext_vector_type(8))) short bf16x8;
typedef __attribute__((ext_vector_type(4))) float f32x4;

__device__ __forceinline__ unsigned short f2bf(float f) {
  unsigned int u = __builtin_bit_cast(unsigned int, f);
  u += 0x7FFFu + ((u >> 16) & 1u);
  return (unsigned short)(u >> 16);
}

__device__ __forceinline__ float bf2f(unsigned short s) {
  return __builtin_bit_cast(float, (unsigned int)s << 16);
}

__device__ __forceinline__ void gload_lds16(const void* g, void* l) {
  __builtin_amdgcn_global_load_lds(
      (__attribute__((address_space(1))) void*)(uintptr_t)g,
      (__attribute__((address_space(3))) void*)l,
      16, 0, 0);
}

#define BARRIER() do { asm volatile("" ::: "memory"); __builtin_amdgcn_s_barrier(); asm volatile("" ::: "memory"); } while (0)
#define WAITVM(N) asm volatile("s_waitcnt vmcnt(" #N ")" ::: "memory")

// ---------------------------------------------------------------------------
// 256x256 tile, BK=64, 8 waves (2M x 4N), 8-phase schedule, counted vmcnt,
// XOR-swizzled LDS (chunk c' = c ^ (row&7)), XCD-contiguous block remap.
// ROUND-5 VERIFIED LOOP (do not restructure). Round-9 change: QUAD issues all
// 8 independent ks=0 MFMAs, then the 8 ks=1 MFMAs (dependent pairs 8 apart ->
// pipe latency hidden), instead of back-to-back dependent pairs.
// C[m,n] = sum_k A[m,k]*B[n,k]. A: MxK bf16 rowmajor, B: NxK bf16 rowmajor.
// MODE 0: bf16 out + f32 bias[n]
// MODE 1: fused row-softmax over N (requires nn==1, N==256): attn bf16 out
// MODE 2: f32 out + bf16 aux (residual)
// ---------------------------------------------------------------------------
template <int MODE>
__global__ __launch_bounds__(512, 2) void gemm8(
    const unsigned short* __restrict__ A, const unsigned short* __restrict__ B,
    void* __restrict__ Cv, const void* __restrict__ aux, int N, int K,
    int nm, int nn, long sAB, long sBB, long sCB, long sXB, float scale)
{
  __shared__ __align__(16) char lds[131072];
  char* ldsc = lds;

  const int tid = threadIdx.x;
  const int lane = tid & 63;
  const int wid = tid >> 6;
  const int fr = lane & 15, fq = lane >> 4;

  const int nwg = gridDim.x;                 // divisible by 8 for all our shapes
  const int id = blockIdx.x;
  const int swz = (id & 7) * (nwg >> 3) + (id >> 3);
  const int per = nm * nn;
  const int t = swz / per;
  const int rem = swz - t * per;
  const int mi_ = rem / nn, ni_ = rem - mi_ * nn;
  const long bm = (long)mi_ * 256, bn = (long)ni_ * 256;

  const unsigned short* Ag = A + (long)t * sAB + bm * K;
  const unsigned short* Bg = B + (long)t * sBB + bn * K;
  const int NT = K >> 6;

  // --- staging source pointers (pre-swizzled global source, linear LDS dest)
  const unsigned short* aS[2][2];
  const unsigned short* bS[2][2];
#pragma unroll
  for (int p = 0; p < 2; ++p) {
    const int q = p * 512 + tid;
    const int lr = q >> 3, cs = q & 7;
    const int cl = cs ^ (lr & 7);
#pragma unroll
    for (int h = 0; h < 2; ++h) {
      const int gA = ((lr >> 6) << 7) | (h << 6) | (lr & 63);
      const int gB = ((lr >> 5) << 6) | (h << 5) | (lr & 31);
      aS[p][h] = Ag + (long)gA * K + cl * 8;
      bS[p][h] = Bg + (long)gB * K + cl * 8;
    }
  }

  // --- swizzled ds_read byte offsets (within a half): row*128 + chunk'*16
  const int c0 = ((fq ^ (fr & 3)) + ((fr >> 2) & 1) * 4) * 16;   // ks=0 chunk
  const int aRd = ((wid >> 2) * 64 + fr) * 128 + c0;  // + mi*16384 + i*2048 (^64 ks=1)
  const int bRd = ((wid & 3) * 32 + fr) * 128 + c0;   // + nj*16384 + j*2048 (^64 ks=1)

  f32x4 acc[2][2][4][2];
#pragma unroll
  for (int a = 0; a < 2; a++)
#pragma unroll
    for (int b = 0; b < 2; b++)
#pragma unroll
      for (int i = 0; i < 4; i++)
#pragma unroll
        for (int j = 0; j < 2; j++)
#pragma unroll
          for (int r = 0; r < 4; r++) acc[a][b][i][j][r] = 0.f;

  bf16x8 af[4][2], bf[2][2][2];

// stage one half-tile (2 x global_load_lds per thread). aoff: 0=A, 32768=B.
#define STAGE(srcArr, aoff, h, ktv, b) do {                                   \
  _Pragma("unroll")                                                           \
  for (int p = 0; p < 2; ++p)                                                 \
    gload_lds16(srcArr[p][h] + ((long)(ktv) << 6),                            \
                ldsc + (aoff) + ((b) << 16) + ((h) << 14) + (p << 13) + (wid << 10)); \
} while (0)

#define LDA(mi, cub) do {                                                     \
  _Pragma("unroll")                                                           \
  for (int i = 0; i < 4; ++i) {                                               \
    af[i][0] = *(const bf16x8*)(ldsc + (cub) + (mi) * 16384 + aRd + i * 2048);        \
    af[i][1] = *(const bf16x8*)(ldsc + (cub) + (mi) * 16384 + (aRd ^ 64) + i * 2048); \
  }                                                                           \
} while (0)

#define LDB(nj, cub) do {                                                     \
  _Pragma("unroll")                                                           \
  for (int j = 0; j < 2; ++j) {                                               \
    bf[nj][j][0] = *(const bf16x8*)(ldsc + 32768 + (cub) + (nj) * 16384 + bRd + j * 2048);        \
    bf[nj][j][1] = *(const bf16x8*)(ldsc + 32768 + (cub) + (nj) * 16384 + (bRd ^ 64) + j * 2048); \
  }                                                                           \
} while (0)

// ks-split: 8 independent MFMAs, then their 8 dependents (8-apart -> hidden)
#define QUAD(mi, nj) do {                                                     \
  __builtin_amdgcn_s_setprio(1);                                              \
  _Pragma("unroll")                                                           \
  for (int i = 0; i < 4; ++i)                                                 \
  _Pragma("unroll")                                                           \
  for (int j = 0; j < 2; ++j)                                                 \
    acc[mi][nj][i][j] = __builtin_amdgcn_mfma_f32_16x16x32_bf16(              \
        af[i][0], bf[nj][j][0], acc[mi][nj][i][j], 0, 0, 0);                  \
  _Pragma("unroll")                                                           \
  for (int i = 0; i < 4; ++i)                                                 \
  _Pragma("unroll")                                                           \
  for (int j = 0; j < 2; ++j)                                                 \
    acc[mi][nj][i][j] = __builtin_amdgcn_mfma_f32_16x16x32_bf16(              \
        af[i][1], bf[nj][j][1], acc[mi][nj][i][j], 0, 0, 0);                  \
  __builtin_amdgcn_s_setprio(0);                                              \
} while (0)

  // --- prologue: kt0 {A0,B0,B1,A1} -> buf0; kt1 {A0,B0,B1} -> buf1
  STAGE(aS, 0, 0, 0, 0);
  STAGE(bS, 32768, 0, 0, 0);
  STAGE(bS, 32768, 1, 0, 0);
  STAGE(aS, 0, 1, 0, 0);
  if (NT > 1) {
    STAGE(aS, 0, 0, 1, 1);
    STAGE(bS, 32768, 0, 1, 1);
    STAGE(bS, 32768, 1, 1, 1);
    WAITVM(6);
  } else {
    WAITVM(0);
  }
  BARRIER();

  for (int kt = 0; kt < NT; ++kt) {
    const int cur = kt & 1, nxt = cur ^ 1;
    const int cub = cur << 16;
    // P0: (mi0,nj0); prefetch kt+1's A1 -> nxt
    LDA(0, cub);
    LDB(0, cub);
    if (kt + 1 < NT) STAGE(aS, 0, 1, kt + 1, nxt);
    BARRIER();
    QUAD(0, 0);
    BARRIER();
    // P1: (mi0,nj1); prefetch kt+2's A0 -> cur (A0 last read in P0)
    LDB(1, cub);
    if (kt + 2 < NT) STAGE(aS, 0, 0, kt + 2, cur);
    BARRIER();
    QUAD(0, 1);
    BARRIER();
    // P2: (mi1,nj0); prefetch kt+2's B0 -> cur (B0 last read in P0)
    LDA(1, cub);
    if (kt + 2 < NT) STAGE(bS, 32768, 0, kt + 2, cur);
    BARRIER();
    QUAD(1, 0);
    BARRIER();
    // P3: (mi1,nj1); prefetch kt+2's B1 -> cur (B1 last read in P1)
    if (kt + 2 < NT) {
      STAGE(bS, 32768, 1, kt + 2, cur);
      QUAD(1, 1);
      WAITVM(6);           // keep 3 half-tiles (kt+2 A0,B0,B1) in flight
    } else {
      QUAD(1, 1);
      WAITVM(0);           // epilogue drain (kt+1's A1 if issued)
    }
    BARRIER();
  }

  // --- epilogue
  if (MODE == 1) {
    // fused row-softmax of (acc*scale) over the full N=256 row; attn bf16 out.
    float* red  = (float*)ldsc;            // [256][4]
    float* red2 = (float*)(ldsc + 4096);   // [256][4]
    const int wc = wid & 3;
    const int rbase = (wid >> 2) * 128;
    // pass 1: per-row wave-partial max (this wave's 64 columns)
#pragma unroll
    for (int mi = 0; mi < 2; ++mi)
#pragma unroll
      for (int i = 0; i < 4; ++i)
#pragma unroll
        for (int r = 0; r < 4; ++r) {
          float m = fmaxf(fmaxf(acc[mi][0][i][0][r], acc[mi][0][i][1][r]),
                          fmaxf(acc[mi][1][i][0][r], acc[mi][1][i][1][r]));
#pragma unroll
          for (int o = 1; o <= 8; o <<= 1) m = fmaxf(m, __shfl_xor(m, o));
          if (fr == 0) red[(rbase + mi * 64 + i * 16 + fq * 4 + r) * 4 + wc] = m;
        }
    BARRIER();
    // pass 2: exp + per-row wave-partial sum
#pragma unroll
    for (int mi = 0; mi < 2; ++mi)
#pragma unroll
      for (int i = 0; i < 4; ++i)
#pragma unroll
        for (int r = 0; r < 4; ++r) {
          const int rl = rbase + mi * 64 + i * 16 + fq * 4 + r;
          f32x4 mm = *(f32x4*)&red[rl * 4];
          const float M = fmaxf(fmaxf(mm[0], mm[1]), fmaxf(mm[2], mm[3]));
          float s = 0.f;
#pragma unroll
          for (int nj = 0; nj < 2; ++nj)
#pragma unroll
            for (int j = 0; j < 2; ++j) {
              float e = __expf((acc[mi][nj][i][j][r] - M) * scale);
              acc[mi][nj][i][j][r] = e;
              s += e;
            }
#pragma unroll
          for (int o = 1; o <= 8; o <<= 1) s += __shfl_xor(s, o);
          if (fr == 0) red2[rl * 4 + wc] = s;
        }
    BARRIER();
    // pass 3: normalize + store bf16
    unsigned short* C = (unsigned short*)Cv + (long)t * sCB;
#pragma unroll
    for (int mi = 0; mi < 2; ++mi)
#pragma unroll
      for (int i = 0; i < 4; ++i)
#pragma unroll
        for (int r = 0; r < 4; ++r) {
          const int rl = rbase + mi * 64 + i * 16 + fq * 4 + r;
          f32x4 sv = *(f32x4*)&red2[rl * 4];
          const float inv = 1.0f / (sv[0] + sv[1] + sv[2] + sv[3]);
          const long gr = bm + rl;
#pragma unroll
          for (int nj = 0; nj < 2; ++nj)
#pragma unroll
            for (int j = 0; j < 2; ++j) {
              const long gcol = bn + wc * 64 + nj * 32 + j * 16 + fr;
              C[gr * N + gcol] = f2bf(acc[mi][nj][i][j][r] * inv);
            }
        }
  } else {
#pragma unroll
    for (int mi = 0; mi < 2; ++mi)
#pragma unroll
      for (int nj = 0; nj < 2; ++nj)
#pragma unroll
        for (int i = 0; i < 4; ++i) {
          const long grow0 = bm + (wid >> 2) * 128 + mi * 64 + i * 16 + fq * 4;
#pragma unroll
          for (int j = 0; j < 2; ++j) {
            const long gcol = bn + (wid & 3) * 64 + nj * 32 + j * 16 + fr;
            if (MODE == 0) {
              unsigned short* C = (unsigned short*)Cv + (long)t * sCB;
              const float bv = ((const float*)aux)[gcol];
#pragma unroll
              for (int r = 0; r < 4; ++r)
                C[(grow0 + r) * N + gcol] = f2bf(acc[mi][nj][i][j][r] + bv);
            } else {
              float* C = (float*)Cv + (long)t * sCB;
              const unsigned short* X = (const unsigned short*)aux + (long)t * sXB;
#pragma unroll
              for (int r = 0; r < 4; ++r) {
                const long idx = (grow0 + r) * N + gcol;
                C[idx] = acc[mi][nj][i][j][r] + bf2f(X[idx]);
              }
            }
          }
        }
  }
#undef STAGE
#undef LDA
#undef LDB
#undef QUAD
}

__global__ __launch_bounds__(256) void convert_f32_bf16(
    const float* __restrict__ in, unsigned short* __restrict__ out, long n) {
  long i = ((long)blockIdx.x * 256 + threadIdx.x) * 4;
  long stride = (long)gridDim.x * 1024;
  for (; i < n; i += stride) {
    float4 v = *(const float4*)(in + i);
    ushort4 o;
    o.x = f2bf(v.x); o.y = f2bf(v.y); o.z = f2bf(v.z); o.w = f2bf(v.w);
    *(ushort4*)(out + i) = o;
  }
}

// slow_feature [64][256][1024] f32 -> slowBf [t][k][d] bf16 AND slowT [t][d][k] bf16
__global__ __launch_bounds__(256) void convert_transpose_slow(
    const float* __restrict__ in, unsigned short* __restrict__ outR,
    unsigned short* __restrict__ outT) {
  __shared__ unsigned short tile[32][33];
  int t = blockIdx.z;
  int d0 = blockIdx.x * 32;
  int k0 = blockIdx.y * 32;
  const float* ip = in + (long)t * 256 * 1024;
  unsigned short* rp = outR + (long)t * 256 * 1024;
  unsigned short* tp = outT + (long)t * 1024 * 256;
  int tx = threadIdx.x & 31, ty = threadIdx.x >> 5;
#pragma unroll
  for (int p = 0; p < 4; p++) {
    int k = ty + p * 8;
    unsigned short b = f2bf(ip[(long)(k0 + k) * 1024 + d0 + tx]);
    tile[k][tx] = b;
    rp[(long)(k0 + k) * 1024 + d0 + tx] = b;
  }
  __syncthreads();
#pragma unroll
  for (int p = 0; p < 4; p++) {
    int d = ty + p * 8;
    tp[(long)(d0 + d) * 256 + k0 + tx] = tile[tx][d];
  }
}

extern "C" void kernel_launch(void* const* d_in, const int* in_sizes, int n_in,
                              void* d_out, int out_size, void* d_ws, size_t ws_size,
                              hipStream_t stream) {
  const float* fastF     = (const float*)d_in[0];  // [64,1024,1024]
  const float* slowF     = (const float*)d_in[1];  // [64,256,1024]
  const float* fastW     = (const float*)d_in[2];  // [1024,1024]
  const float* fast_bias = (const float*)d_in[3];  // [1024]
  const float* slowW     = (const float*)d_in[4];  // [1024,1024]
  const float* slow_bias = (const float*)d_in[5];  // [1024]
  float* out = (float*)d_out;

  char* ws = (char*)d_ws;
  // layout: fastBf [0,128M) alive until ctx (residual); fastKey [128M,256M);
  // attnBf [256M,288M) over dead slowBf; slowT [288M,320M);
  // slowKey [320M,352M); weights at 352M+.
  unsigned short* fastBf  = (unsigned short*)(ws);
  unsigned short* fastKey = (unsigned short*)(ws + 134217728L);
  unsigned short* slowBf  = (unsigned short*)(ws + 268435456L);
  unsigned short* attnBf  = (unsigned short*)(ws + 268435456L);  // reuses slowBf
  unsigned short* slowT   = (unsigned short*)(ws + 301989888L);
  unsigned short* slowKey = (unsigned short*)(ws + 335544320L);
  unsigned short* fWb     = (unsigned short*)(ws + 369098752L);
  unsigned short* sWb     = (unsigned short*)(ws + 371195904L);

  convert_f32_bf16<<<2048, 256, 0, stream>>>(fastF, fastBf, 67108864L);
  convert_f32_bf16<<<1024, 256, 0, stream>>>(fastW, fWb, 1048576L);
  convert_f32_bf16<<<1024, 256, 0, stream>>>(slowW, sWb, 1048576L);
  convert_transpose_slow<<<dim3(32, 8, 64), 256, 0, stream>>>(slowF, slowBf, slowT);

  // slow_key = slow @ slowW^T + slow_b : M=16384, N=1024, K=1024 (NT=16)
  gemm8<0><<<64 * 4, 512, 0, stream>>>(slowBf, sWb, slowKey, slow_bias,
      1024, 1024, 64, 4, 0, 0, 0, 0, 1.f);
  // fast_key = fast @ fastW^T + fast_b : M=65536, N=1024, K=1024 (NT=16)
  gemm8<0><<<256 * 4, 512, 0, stream>>>(fastBf, fWb, fastKey, fast_bias,
      1024, 1024, 256, 4, 0, 0, 0, 0, 1.f);
  // attn[t] = softmax(fast_key[t] @ slow_key[t]^T / 32) : M=1024, N=256, K=1024 (NT=16)
  gemm8<1><<<4 * 1 * 64, 512, 0, stream>>>(fastKey, slowKey, attnBf, nullptr,
      256, 1024, 4, 1, 1048576L, 262144L, 262144L, 0, 0.03125f);
  // out[t] = attn[t] @ slow_T[t]^T + bf16(fast[t]) : M=1024, N=1024, K=256 (NT=4)
  gemm8<2><<<4 * 4 * 64, 512, 0, stream>>>(attnBf, slowT, out, fastBf,
      1024, 256, 4, 4, 262144L, 262144L, 1048576L, 1048576L, 1.f);
}